// Round 1
// baseline (290.205 us; speedup 1.0000x reference)
//
#include <hip/hip_runtime.h>
#include <cstdint>
#include <cstddef>

// Problem shape (fixed by the reference): B=8, S=2048, D=512, fp32 in/out.
#define B_ 8
#define S_ 2048
#define D_ 512

typedef float f32x4 __attribute__((ext_vector_type(4)));
typedef __bf16 bf16x8 __attribute__((ext_vector_type(8)));

// fp32 -> bf16 round-to-nearest-even
__device__ __forceinline__ unsigned short f2bf(float f) {
    unsigned u = __builtin_bit_cast(unsigned, f);
    u += 0x7FFFu + ((u >> 16) & 1u);
    return (unsigned short)(u >> 16);
}

// async global->LDS, 16B per lane. LDS dest is wave-uniform base + lane*16.
__device__ __forceinline__ void gld_lds16(const void* g, void* l) {
    __builtin_amdgcn_global_load_lds(
        (__attribute__((address_space(1))) void*)g,
        (__attribute__((address_space(3))) void*)l,
        16, 0, 0);
}

// ---------------------------------------------------------------------------
// Generic bf16 GEMM, C = scale * (A @ B^T-layout-B):
//   A: [M x K] bf16 row-major (k contiguous)
//   B: [N x K] bf16 row-major (k contiguous)  == B^T of the math B[K x N]
//   C: [M x N], bf16 (out_bf16=1) or fp32 (out_bf16=0)
// 128x128 tile, BK=32, 4 waves 2x2, 16x16x32 bf16 MFMA, 4x4 acc per wave.
// Requires M,N multiples of 128; K multiple of 32. blockIdx.z batches via
// element strides sA/sB/sC.
// ---------------------------------------------------------------------------
__global__ __launch_bounds__(256) void gemm_bt(
    const unsigned short* __restrict__ A,
    const unsigned short* __restrict__ B,
    void* __restrict__ Cv,
    int K, int lda, int ldb, int ldc,
    long long sA, long long sB, long long sC,
    float scale, int out_bf16)
{
    __shared__ __align__(16) unsigned short lA[128 * 32];  // [m][k], 8 KB
    __shared__ __align__(16) unsigned short lB[128 * 32];  // [n][k], 8 KB

    A += (long long)blockIdx.z * sA;
    B += (long long)blockIdx.z * sB;
    const int m0 = blockIdx.y * 128;
    const int n0 = blockIdx.x * 128;
    const int tid  = threadIdx.x;
    const int lane = tid & 63;
    const int wave = tid >> 6;
    const int wm = (wave & 1) * 64;   // wave's 64x64 sub-tile
    const int wn = (wave >> 1) * 64;

    f32x4 acc[4][4] = {};

    // Staging: tile is 128 rows x 64 bytes. Each wave issues 2 calls of
    // 64 lanes x 16B = 1024 B, contiguous in LDS ([row][k] row-major).
    const int bo0 = wave * 2048;        // LDS byte base, call 0
    const int bo1 = bo0 + 1024;         // call 1
    const int o0 = bo0 + lane * 16;     // this lane's LDS byte (implicit)
    const int o1 = bo1 + lane * 16;
    const int r0 = o0 >> 6, c0 = (o0 & 63) >> 1;   // row, element-col
    const int r1 = o1 >> 6, c1 = (o1 & 63) >> 1;

    const unsigned short* A0 = A + (size_t)(m0 + r0) * lda + c0;
    const unsigned short* A1 = A + (size_t)(m0 + r1) * lda + c1;
    const unsigned short* B0 = B + (size_t)(n0 + r0) * ldb + c0;
    const unsigned short* B1 = B + (size_t)(n0 + r1) * ldb + c1;

    char* lAc = (char*)lA;
    char* lBc = (char*)lB;

    // fragment geometry: A[m=lane&15][k=(lane>>4)*8 + j], B symmetric
    const int fr  = lane & 15;
    const int fko = (lane >> 4) * 8;

    for (int k0 = 0; k0 < K; k0 += 32) {
        __syncthreads();   // protect LDS from overwrite while in use
        gld_lds16(A0 + k0, lAc + bo0);
        gld_lds16(A1 + k0, lAc + bo1);
        gld_lds16(B0 + k0, lBc + bo0);
        gld_lds16(B1 + k0, lBc + bo1);
        __syncthreads();   // drains vmcnt before barrier (compiler-inserted)

        bf16x8 af[4], bfr[4];
        #pragma unroll
        for (int t = 0; t < 4; ++t) {
            af[t]  = *(const bf16x8*)&lA[(wm + t * 16 + fr) * 32 + fko];
            bfr[t] = *(const bf16x8*)&lB[(wn + t * 16 + fr) * 32 + fko];
        }
        #pragma unroll
        for (int mt = 0; mt < 4; ++mt)
            #pragma unroll
            for (int nt = 0; nt < 4; ++nt)
                acc[mt][nt] = __builtin_amdgcn_mfma_f32_16x16x32_bf16(
                    af[mt], bfr[nt], acc[mt][nt], 0, 0, 0);
    }

    // Epilogue. C/D layout (m89-verified): col = lane&15, row = (lane>>4)*4+r
    const int col = lane & 15;
    const int rb  = (lane >> 4) * 4;
    if (out_bf16) {
        unsigned short* C = (unsigned short*)Cv + (long long)blockIdx.z * sC;
        #pragma unroll
        for (int mt = 0; mt < 4; ++mt) {
            #pragma unroll
            for (int nt = 0; nt < 4; ++nt) {
                const int gc = n0 + wn + nt * 16 + col;
                #pragma unroll
                for (int r = 0; r < 4; ++r) {
                    const int gr = m0 + wm + mt * 16 + rb + r;
                    C[(size_t)gr * ldc + gc] = f2bf(acc[mt][nt][r] * scale);
                }
            }
        }
    } else {
        float* C = (float*)Cv + (long long)blockIdx.z * sC;
        #pragma unroll
        for (int mt = 0; mt < 4; ++mt) {
            #pragma unroll
            for (int nt = 0; nt < 4; ++nt) {
                const int gc = n0 + wn + nt * 16 + col;
                #pragma unroll
                for (int r = 0; r < 4; ++r) {
                    const int gr = m0 + wm + mt * 16 + rb + r;
                    C[(size_t)gr * ldc + gc] = acc[mt][nt][r] * scale;
                }
            }
        }
    }
}

// ---------------------------------------------------------------------------
// fp32 -> bf16 convert, 4 elems/thread
// ---------------------------------------------------------------------------
__global__ __launch_bounds__(256) void convert_x4(const float* __restrict__ x,
                                                  unsigned short* __restrict__ xb) {
    const size_t i = ((size_t)blockIdx.x * 256 + threadIdx.x) * 4;
    const float4 f = *(const float4*)(x + i);
    ushort4 u;
    u.x = f2bf(f.x); u.y = f2bf(f.y); u.z = f2bf(f.z); u.w = f2bf(f.w);
    *(ushort4*)(xb + i) = u;
}

// W [D][D] (d,e) -> WT bf16 [e][d]; blockIdx.y selects WQ/WK/WV.
// Reads are d-strided but W (1 MB) lives in L2 — negligible cost.
__global__ __launch_bounds__(256) void convert_w(const float* __restrict__ WQ,
                                                 const float* __restrict__ WK,
                                                 const float* __restrict__ WV,
                                                 unsigned short* __restrict__ WT) {
    const int o = blockIdx.x * 256 + threadIdx.x;   // 0..D*D-1
    const float* W = blockIdx.y == 0 ? WQ : (blockIdx.y == 1 ? WK : WV);
    const int e = o >> 9, d = o & (D_ - 1);
    WT[(size_t)blockIdx.y * D_ * D_ + o] = f2bf(W[d * D_ + e]);
}

// V [b][s][d] -> VT [b][d][s], LDS 32x32 tiles (both sides coalesced)
__global__ __launch_bounds__(256) void transpose_v(const unsigned short* __restrict__ V,
                                                   unsigned short* __restrict__ VT) {
    __shared__ unsigned short t[32][33];
    const int b  = blockIdx.z;
    const int s0 = blockIdx.x * 32;
    const int d0 = blockIdx.y * 32;
    const int tx = threadIdx.x & 31;
    const int ty = threadIdx.x >> 5;   // 0..7
    const unsigned short* Vb = V + (size_t)b * S_ * D_;
    unsigned short* VTb = VT + (size_t)b * S_ * D_;
    #pragma unroll
    for (int j = 0; j < 32; j += 8)
        t[ty + j][tx] = Vb[(size_t)(s0 + ty + j) * D_ + d0 + tx];
    __syncthreads();
    #pragma unroll
    for (int j = 0; j < 32; j += 8)
        VTb[(size_t)(d0 + ty + j) * S_ + s0 + tx] = t[tx][ty + j];
}

// ---------------------------------------------------------------------------
// Row softmax over S_ bf16 scores, in place. One block per row, 8 elems/thread,
// fp32 math, block reduce (wave shuffle + 4-slot LDS).
// ---------------------------------------------------------------------------
__global__ __launch_bounds__(256) void softmax_rows(unsigned short* __restrict__ Smat) {
    const int tid = threadIdx.x;
    unsigned short* row = Smat + (size_t)blockIdx.x * S_;
    const uint4 raw = *(const uint4*)(row + tid * 8);
    const unsigned ru[4] = {raw.x, raw.y, raw.z, raw.w};
    float v[8];
    #pragma unroll
    for (int i = 0; i < 4; ++i) {
        v[2 * i]     = __builtin_bit_cast(float, (ru[i] & 0xFFFFu) << 16);
        v[2 * i + 1] = __builtin_bit_cast(float, ru[i] & 0xFFFF0000u);
    }
    float m = v[0];
    #pragma unroll
    for (int i = 1; i < 8; ++i) m = fmaxf(m, v[i]);
    #pragma unroll
    for (int off = 32; off > 0; off >>= 1) m = fmaxf(m, __shfl_xor(m, off, 64));
    __shared__ float red[4];
    const int wave = tid >> 6, lane = tid & 63;
    if (lane == 0) red[wave] = m;
    __syncthreads();
    m = fmaxf(fmaxf(red[0], red[1]), fmaxf(red[2], red[3]));

    float e[8], s = 0.f;
    #pragma unroll
    for (int i = 0; i < 8; ++i) { e[i] = __expf(v[i] - m); s += e[i]; }
    #pragma unroll
    for (int off = 32; off > 0; off >>= 1) s += __shfl_xor(s, off, 64);
    __syncthreads();
    if (lane == 0) red[wave] = s;
    __syncthreads();
    const float inv = 1.0f / (red[0] + red[1] + red[2] + red[3]);

    uint4 o;
    unsigned ov[4];
    #pragma unroll
    for (int i = 0; i < 4; ++i)
        ov[i] = (unsigned)f2bf(e[2 * i] * inv) |
                ((unsigned)f2bf(e[2 * i + 1] * inv) << 16);
    o.x = ov[0]; o.y = ov[1]; o.z = ov[2]; o.w = ov[3];
    *(uint4*)(row + tid * 8) = o;
}

// ---------------------------------------------------------------------------
extern "C" void kernel_launch(void* const* d_in, const int* in_sizes, int n_in,
                              void* d_out, int out_size, void* d_ws, size_t ws_size,
                              hipStream_t stream)
{
    const float* x  = (const float*)d_in[0];
    const float* WQ = (const float*)d_in[1];
    const float* WK = (const float*)d_in[2];
    const float* WV = (const float*)d_in[3];

    // workspace layout (bf16 elements); total ~145.5 MB
    unsigned short* ws  = (unsigned short*)d_ws;
    const size_t NX = (size_t)B_ * S_ * D_;          // 8,388,608
    unsigned short* xb  = ws;                        // [16384][512]
    unsigned short* wtb = xb + NX;                   // 3 x [512 e][512 d]
    unsigned short* qb  = wtb + 3 * D_ * D_;         // [b][s][d]
    unsigned short* kb  = qb + NX;                   // [b][s][d]
    unsigned short* vb  = kb + NX;                   // [b][s][d]
    unsigned short* vtb = vb + NX;                   // [b][d][s]
    unsigned short* sb  = vtb + NX;                  // [b][q][k] scores/P

    // 1) converts
    convert_x4<<<dim3((unsigned)(NX / 4 / 256)), 256, 0, stream>>>(x, xb);
    convert_w<<<dim3(D_ * D_ / 256, 3), 256, 0, stream>>>(WQ, WK, WV, wtb);

    // 2) QKV projections: [16384 x 512] = xb @ W  (W^T rows are n, k contig)
    gemm_bt<<<dim3(D_ / 128, (B_ * S_) / 128, 1), 256, 0, stream>>>(
        xb, wtb,             qb, D_, D_, D_, D_, 0, 0, 0, 1.0f, 1);
    gemm_bt<<<dim3(D_ / 128, (B_ * S_) / 128, 1), 256, 0, stream>>>(
        xb, wtb + D_ * D_,   kb, D_, D_, D_, D_, 0, 0, 0, 1.0f, 1);
    gemm_bt<<<dim3(D_ / 128, (B_ * S_) / 128, 1), 256, 0, stream>>>(
        xb, wtb + 2 * D_ * D_, vb, D_, D_, D_, D_, 0, 0, 0, 1.0f, 1);

    // 3) V -> V^T for the PV GEMM's B^T operand
    transpose_v<<<dim3(S_ / 32, D_ / 32, B_), 256, 0, stream>>>(vb, vtb);

    // 4) scores = Q @ K^T * 1/sqrt(D), bf16, per batch
    gemm_bt<<<dim3(S_ / 128, S_ / 128, B_), 256, 0, stream>>>(
        qb, kb, sb, D_, D_, D_, S_,
        (long long)S_ * D_, (long long)S_ * D_, (long long)S_ * S_,
        0.04419417382415922f, 1);

    // 5) softmax rows, in place (bf16)
    softmax_rows<<<dim3(B_ * S_), 256, 0, stream>>>(sb);

    // 6) out = P @ V (fp32 out), B^T operand = V^T [d][key]
    gemm_bt<<<dim3(D_ / 128, S_ / 128, B_), 256, 0, stream>>>(
        sb, vtb, d_out, S_, S_, S_, D_,
        (long long)S_ * S_, (long long)S_ * D_, (long long)S_ * D_,
        1.0f, 0);
}

// Round 2
// 263.585 us; speedup vs baseline: 1.1010x; 1.1010x over previous
//
#include <hip/hip_runtime.h>
#include <cstdint>
#include <cstddef>

// Problem shape (fixed by the reference): B=8, S=2048, D=512, fp32 in/out.
#define B_ 8
#define S_ 2048
#define D_ 512

typedef float f32x4 __attribute__((ext_vector_type(4)));
typedef __bf16 bf16x8 __attribute__((ext_vector_type(8)));

// fp32 -> bf16 round-to-nearest-even
__device__ __forceinline__ unsigned short f2bf(float f) {
    unsigned u = __builtin_bit_cast(unsigned, f);
    u += 0x7FFFu + ((u >> 16) & 1u);
    return (unsigned short)(u >> 16);
}

// async global->LDS, 16B per lane. LDS dest is wave-uniform base + lane*16.
__device__ __forceinline__ void gld_lds16(const void* g, void* l) {
    __builtin_amdgcn_global_load_lds(
        (__attribute__((address_space(1))) void*)g,
        (__attribute__((address_space(3))) void*)l,
        16, 0, 0);
}

// ---------------------------------------------------------------------------
// Generic bf16 GEMM, C = scale * (A @ B^T-layout-B):
//   A: [M x K] bf16 row-major (k contiguous), leading dim lda
//   B: [N x K] bf16 row-major (k contiguous), leading dim ldb
//   C: [M x N], bf16 (out_bf16=1) or fp32 (out_bf16=0)
// 128x128 tile, BK=32, 4 waves 2x2, 16x16x32 bf16 MFMA, 4x4 acc per wave.
//
// Grid is 1-D: nbatch * ntm * ntn blocks. Decode pins batch = blockIdx%nbatch
// so each batch's working set stays in ONE XCD's L2 (XCD = wgid % 8 heuristic).
//
// LDS k-chunk XOR swizzle: physical 16B chunk p of row r holds logical chunk
// p ^ (r & 3). Applied on the global source address (global_load_lds's LDS
// dest is fixed contiguous), undone at ds_read time. Breaks the 64B-row-stride
// bank aliasing of the plain layout.
// ---------------------------------------------------------------------------
__global__ __launch_bounds__(256) void gemm_bt(
    const unsigned short* __restrict__ A,
    const unsigned short* __restrict__ B,
    void* __restrict__ Cv,
    int K, int lda, int ldb, int ldc,
    long long sA, long long sB, long long sC,
    float scale, int out_bf16, int ntn, int nbatch)
{
    __shared__ __align__(16) unsigned short lA[128 * 32];  // [m][k], 8 KB
    __shared__ __align__(16) unsigned short lB[128 * 32];  // [n][k], 8 KB

    const int lin = blockIdx.x;
    const int bz  = lin % nbatch;        // batch -> XCD pin
    const int t   = lin / nbatch;
    const int tn  = t % ntn;
    const int tm  = t / ntn;

    A += (long long)bz * sA;
    B += (long long)bz * sB;
    const int m0 = tm * 128;
    const int n0 = tn * 128;
    const int tid  = threadIdx.x;
    const int lane = tid & 63;
    const int wave = tid >> 6;
    const int wm = (wave & 1) * 64;   // wave's 64x64 sub-tile
    const int wn = (wave >> 1) * 64;

    f32x4 acc[4][4] = {};

    // Staging: tile is 128 rows x 64 bytes. Each wave issues 2 calls of
    // 64 lanes x 16B = 1024 B, contiguous in LDS ([row][k] row-major,
    // k-chunks XOR-swizzled per row).
    const int bo0 = wave * 2048;        // LDS byte base, call 0
    const int bo1 = bo0 + 1024;         // call 1
    const int o0 = bo0 + lane * 16;     // this lane's LDS byte (implicit)
    const int o1 = bo1 + lane * 16;
    const int r0 = o0 >> 6, cp0 = (o0 & 63) >> 4;   // row, physical chunk
    const int r1 = o1 >> 6, cp1 = (o1 & 63) >> 4;
    const int c0 = (cp0 ^ (r0 & 3)) << 3;           // logical element col
    const int c1 = (cp1 ^ (r1 & 3)) << 3;

    const unsigned short* A0 = A + (size_t)(m0 + r0) * lda + c0;
    const unsigned short* A1 = A + (size_t)(m0 + r1) * lda + c1;
    const unsigned short* B0 = B + (size_t)(n0 + r0) * ldb + c0;
    const unsigned short* B1 = B + (size_t)(n0 + r1) * ldb + c1;

    char* lAc = (char*)lA;
    char* lBc = (char*)lB;

    // fragment geometry: A[m=lane&15][k=(lane>>4)*8 + j], B symmetric.
    // Row r's logical k-chunk g sits at physical chunk g ^ (r&3); all rows a
    // fragment touches have r&3 == fr&3.
    const int fr  = lane & 15;
    const int g   = lane >> 4;                 // logical k-chunk 0..3
    const int sx  = (g ^ (fr & 3)) << 3;       // swizzled element offset

    for (int k0 = 0; k0 < K; k0 += 32) {
        __syncthreads();   // protect LDS from overwrite while in use
        gld_lds16(A0 + k0, lAc + bo0);
        gld_lds16(A1 + k0, lAc + bo1);
        gld_lds16(B0 + k0, lBc + bo0);
        gld_lds16(B1 + k0, lBc + bo1);
        __syncthreads();   // drains vmcnt before barrier (compiler-inserted)

        bf16x8 af[4], bfr[4];
        #pragma unroll
        for (int tt = 0; tt < 4; ++tt) {
            af[tt]  = *(const bf16x8*)&lA[(wm + tt * 16 + fr) * 32 + sx];
            bfr[tt] = *(const bf16x8*)&lB[(wn + tt * 16 + fr) * 32 + sx];
        }
        #pragma unroll
        for (int mt = 0; mt < 4; ++mt)
            #pragma unroll
            for (int nt = 0; nt < 4; ++nt)
                acc[mt][nt] = __builtin_amdgcn_mfma_f32_16x16x32_bf16(
                    af[mt], bfr[nt], acc[mt][nt], 0, 0, 0);
    }

    // Epilogue. C/D layout (m89-verified): col = lane&15, row = (lane>>4)*4+r
    const int col = lane & 15;
    const int rb  = (lane >> 4) * 4;
    if (out_bf16) {
        unsigned short* C = (unsigned short*)Cv + (long long)bz * sC;
        #pragma unroll
        for (int mt = 0; mt < 4; ++mt) {
            #pragma unroll
            for (int nt = 0; nt < 4; ++nt) {
                const int gc = n0 + wn + nt * 16 + col;
                #pragma unroll
                for (int r = 0; r < 4; ++r) {
                    const int gr = m0 + wm + mt * 16 + rb + r;
                    C[(size_t)gr * ldc + gc] = f2bf(acc[mt][nt][r] * scale);
                }
            }
        }
    } else {
        float* C = (float*)Cv + (long long)bz * sC;
        #pragma unroll
        for (int mt = 0; mt < 4; ++mt) {
            #pragma unroll
            for (int nt = 0; nt < 4; ++nt) {
                const int gc = n0 + wn + nt * 16 + col;
                #pragma unroll
                for (int r = 0; r < 4; ++r) {
                    const int gr = m0 + wm + mt * 16 + rb + r;
                    C[(size_t)gr * ldc + gc] = acc[mt][nt][r] * scale;
                }
            }
        }
    }
}

// ---------------------------------------------------------------------------
// fp32 -> bf16 convert, 4 elems/thread
// ---------------------------------------------------------------------------
__global__ __launch_bounds__(256) void convert_x4(const float* __restrict__ x,
                                                  unsigned short* __restrict__ xb) {
    const size_t i = ((size_t)blockIdx.x * 256 + threadIdx.x) * 4;
    const float4 f = *(const float4*)(x + i);
    ushort4 u;
    u.x = f2bf(f.x); u.y = f2bf(f.y); u.z = f2bf(f.z); u.w = f2bf(f.w);
    *(ushort4*)(xb + i) = u;
}

// W [D][D] (d,e) -> WT bf16 rows e (n), cols d (k); the three weights stack
// into one [3*D][D] B-operand for the merged QKV GEMM.
__global__ __launch_bounds__(256) void convert_w(const float* __restrict__ WQ,
                                                 const float* __restrict__ WK,
                                                 const float* __restrict__ WV,
                                                 unsigned short* __restrict__ WT) {
    const int o = blockIdx.x * 256 + threadIdx.x;   // 0..D*D-1
    const float* W = blockIdx.y == 0 ? WQ : (blockIdx.y == 1 ? WK : WV);
    const int e = o >> 9, d = o & (D_ - 1);
    WT[(size_t)blockIdx.y * D_ * D_ + o] = f2bf(W[d * D_ + e]);
}

// V (rows of qkv at col offset 1024, ld=1536) -> VT [b][d][s], 32x32 LDS tiles
__global__ __launch_bounds__(256) void transpose_v(const unsigned short* __restrict__ V,
                                                   int ldv,
                                                   unsigned short* __restrict__ VT) {
    __shared__ unsigned short t[32][33];
    const int b  = blockIdx.z;
    const int s0 = blockIdx.x * 32;
    const int d0 = blockIdx.y * 32;
    const int tx = threadIdx.x & 31;
    const int ty = threadIdx.x >> 5;   // 0..7
    const unsigned short* Vb = V + (size_t)b * S_ * ldv;
    unsigned short* VTb = VT + (size_t)b * S_ * D_;
    #pragma unroll
    for (int j = 0; j < 32; j += 8)
        t[ty + j][tx] = Vb[(size_t)(s0 + ty + j) * ldv + d0 + tx];
    __syncthreads();
    #pragma unroll
    for (int j = 0; j < 32; j += 8)
        VTb[(size_t)(d0 + ty + j) * S_ + s0 + tx] = t[tx][ty + j];
}

// ---------------------------------------------------------------------------
// Row softmax over S_ bf16 scores, in place. One block per row, 8 elems/thread,
// fp32 math, block reduce (wave shuffle + 4-slot LDS).
// ---------------------------------------------------------------------------
__global__ __launch_bounds__(256) void softmax_rows(unsigned short* __restrict__ Smat) {
    const int tid = threadIdx.x;
    unsigned short* row = Smat + (size_t)blockIdx.x * S_;
    const uint4 raw = *(const uint4*)(row + tid * 8);
    const unsigned ru[4] = {raw.x, raw.y, raw.z, raw.w};
    float v[8];
    #pragma unroll
    for (int i = 0; i < 4; ++i) {
        v[2 * i]     = __builtin_bit_cast(float, (ru[i] & 0xFFFFu) << 16);
        v[2 * i + 1] = __builtin_bit_cast(float, ru[i] & 0xFFFF0000u);
    }
    float m = v[0];
    #pragma unroll
    for (int i = 1; i < 8; ++i) m = fmaxf(m, v[i]);
    #pragma unroll
    for (int off = 32; off > 0; off >>= 1) m = fmaxf(m, __shfl_xor(m, off, 64));
    __shared__ float red[4];
    const int wave = tid >> 6, lane = tid & 63;
    if (lane == 0) red[wave] = m;
    __syncthreads();
    m = fmaxf(fmaxf(red[0], red[1]), fmaxf(red[2], red[3]));

    float e[8], s = 0.f;
    #pragma unroll
    for (int i = 0; i < 8; ++i) { e[i] = __expf(v[i] - m); s += e[i]; }
    #pragma unroll
    for (int off = 32; off > 0; off >>= 1) s += __shfl_xor(s, off, 64);
    __syncthreads();
    if (lane == 0) red[wave] = s;
    __syncthreads();
    const float inv = 1.0f / (red[0] + red[1] + red[2] + red[3]);

    uint4 o;
    unsigned ov[4];
    #pragma unroll
    for (int i = 0; i < 4; ++i)
        ov[i] = (unsigned)f2bf(e[2 * i] * inv) |
                ((unsigned)f2bf(e[2 * i + 1] * inv) << 16);
    o.x = ov[0]; o.y = ov[1]; o.z = ov[2]; o.w = ov[3];
    *(uint4*)(row + tid * 8) = o;
}

// ---------------------------------------------------------------------------
extern "C" void kernel_launch(void* const* d_in, const int* in_sizes, int n_in,
                              void* d_out, int out_size, void* d_ws, size_t ws_size,
                              hipStream_t stream)
{
    const float* x  = (const float*)d_in[0];
    const float* WQ = (const float*)d_in[1];
    const float* WK = (const float*)d_in[2];
    const float* WV = (const float*)d_in[3];

    // workspace layout (bf16 elements); ~148 MB total
    unsigned short* ws  = (unsigned short*)d_ws;
    const size_t NX = (size_t)B_ * S_ * D_;          // 8,388,608
    unsigned short* xb  = ws;                        // [16384][512]
    unsigned short* wtb = xb + NX;                   // [1536 n][512 k] stacked QKV weights
    unsigned short* qkv = wtb + 3 * D_ * D_;         // [16384][1536] (Q|K|V per row)
    unsigned short* vtb = qkv + NX * 3;              // [b][d][s]
    unsigned short* sb  = vtb + NX;                  // [b][q][k] scores/P

    // 1) converts
    convert_x4<<<dim3((unsigned)(NX / 4 / 256)), 256, 0, stream>>>(x, xb);
    convert_w<<<dim3(D_ * D_ / 256, 3), 256, 0, stream>>>(WQ, WK, WV, wtb);

    // 2) merged QKV projection: [16384 x 1536] = xb @ [WQ|WK|WV]
    gemm_bt<<<dim3((B_ * S_ / 128) * (3 * D_ / 128)), 256, 0, stream>>>(
        xb, wtb, qkv, D_, D_, D_, 3 * D_,
        0, 0, 0, 1.0f, 1, /*ntn*/ 3 * D_ / 128, /*nbatch*/ 1);

    // 3) V -> V^T for the PV GEMM's B^T operand
    transpose_v<<<dim3(S_ / 32, D_ / 32, B_), 256, 0, stream>>>(
        qkv + 2 * D_, 3 * D_, vtb);

    // 4) scores = Q @ K^T * 1/sqrt(D), bf16, per batch (batch pinned to XCD)
    gemm_bt<<<dim3(B_ * (S_ / 128) * (S_ / 128)), 256, 0, stream>>>(
        qkv /*Q*/, qkv + D_ /*K*/, sb, D_, 3 * D_, 3 * D_, S_,
        (long long)S_ * 3 * D_, (long long)S_ * 3 * D_, (long long)S_ * S_,
        0.04419417382415922f, 1, /*ntn*/ S_ / 128, /*nbatch*/ B_);

    // 5) softmax rows, in place (bf16)
    softmax_rows<<<dim3(B_ * S_), 256, 0, stream>>>(sb);

    // 6) out = P @ V (fp32 out), B^T operand = V^T [d][key]
    gemm_bt<<<dim3(B_ * (S_ / 128) * (D_ / 128)), 256, 0, stream>>>(
        sb, vtb, d_out, S_, S_, S_, D_,
        (long long)S_ * S_, (long long)S_ * D_, (long long)S_ * D_,
        1.0f, 0, /*ntn*/ D_ / 128, /*nbatch*/ B_);
}

// Round 3
// 258.001 us; speedup vs baseline: 1.1248x; 1.0216x over previous
//
#include <hip/hip_runtime.h>
#include <cstdint>
#include <cstddef>

// Problem shape (fixed by the reference): B=8, S=2048, D=512, fp32 in/out.
#define B_ 8
#define S_ 2048
#define D_ 512

typedef float f32x16 __attribute__((ext_vector_type(16)));
typedef __bf16 bf16x8 __attribute__((ext_vector_type(8)));

// fp32 -> bf16 round-to-nearest-even
__device__ __forceinline__ unsigned short f2bf(float f) {
    unsigned u = __builtin_bit_cast(unsigned, f);
    u += 0x7FFFu + ((u >> 16) & 1u);
    return (unsigned short)(u >> 16);
}

// async global->LDS, 16B per lane. LDS dest is wave-uniform base + lane*16.
__device__ __forceinline__ void gld_lds16(const void* g, void* l) {
    __builtin_amdgcn_global_load_lds(
        (__attribute__((address_space(1))) void*)g,
        (__attribute__((address_space(3))) void*)l,
        16, 0, 0);
}

// ---------------------------------------------------------------------------
// bf16 GEMM, C = scale * (A @ B^T-layout-B):
//   A: [M x K] bf16 row-major (k contiguous), leading dim lda
//   B: [N x K] bf16 row-major (k contiguous), leading dim ldb
// 128x128 tile, BK=32, 4 waves 2x2 (64x64/wave), 32x32x16 bf16 MFMA (2x2 acc
// tiles/wave, 19% better FLOP/cyc than 16x16x32 per m119).
//
// Grid 1-D: nbatch*ntm*ntn blocks; batch = blockIdx % nbatch pins each batch's
// working set to one XCD's L2 (round-2 verified: FETCH 147->29 MB).
//
// LDS swizzle: physical 16B chunk p of row r holds logical chunk p ^ ((r>>1)&3).
// ds_read_b128 is serviced in 8-lane phases; lane fr's bank-group start is
// (fr*16 + chunk*4) mod 32 — evens start at 0, odds at 16. (r>>1)&3 assigns
// distinct chunks within each parity class -> all 32 banks tiled once.
// (Round-2's r&3 left evens at {0,2,0,2}: conflicts unchanged at 4.19M.)
// Applied on the global source address (global_load_lds dest is fixed
// contiguous), undone at ds_read time.
//
// mode: 0 = fp32 C out; 1 = bf16 C out; 2 = QKV fused: tiles tn<8 write bf16
// Q|K to Cv (ldc), tiles tn>=8 write V TRANSPOSED+packed (ushort4) to Cv2 as
// [b][d][s] — reg-quads cover 4 consecutive rows -> 4 consecutive s.
// ---------------------------------------------------------------------------
__global__ __launch_bounds__(256) void gemm_bt(
    const unsigned short* __restrict__ A,
    const unsigned short* __restrict__ B,
    void* __restrict__ Cv,
    unsigned short* __restrict__ Cv2,
    int K, int lda, int ldb, int ldc,
    long long sA, long long sB, long long sC,
    float scale, int mode, int ntn, int nbatch)
{
    __shared__ __align__(16) unsigned short lA[128 * 32];  // [m][k], 8 KB
    __shared__ __align__(16) unsigned short lB[128 * 32];  // [n][k], 8 KB

    const int lin = blockIdx.x;
    const int bz  = lin % nbatch;        // batch -> XCD pin
    const int t   = lin / nbatch;
    const int tn  = t % ntn;
    const int tm  = t / ntn;

    A += (long long)bz * sA;
    B += (long long)bz * sB;
    const int m0 = tm * 128;
    const int n0 = tn * 128;
    const int tid  = threadIdx.x;
    const int lane = tid & 63;
    const int wave = tid >> 6;
    const int wm = (wave & 1) * 64;   // wave's 64x64 sub-tile
    const int wn = (wave >> 1) * 64;

    f32x16 acc[2][2] = {};

    // Staging: tile is 128 rows x 64 bytes. Each wave: 2 calls x 64 lanes x 16B,
    // contiguous in LDS. Swizzle on the global source column.
    const int bo0 = wave * 2048;
    const int bo1 = bo0 + 1024;
    const int o0 = bo0 + lane * 16;
    const int o1 = bo1 + lane * 16;
    const int r0 = o0 >> 6, cp0 = (o0 & 63) >> 4;
    const int r1 = o1 >> 6, cp1 = (o1 & 63) >> 4;
    const int c0 = (cp0 ^ ((r0 >> 1) & 3)) << 3;   // logical element col
    const int c1 = (cp1 ^ ((r1 >> 1) & 3)) << 3;

    const unsigned short* A0 = A + (size_t)(m0 + r0) * lda + c0;
    const unsigned short* A1 = A + (size_t)(m0 + r1) * lda + c1;
    const unsigned short* B0 = B + (size_t)(n0 + r0) * ldb + c0;
    const unsigned short* B1 = B + (size_t)(n0 + r1) * ldb + c1;

    char* lAc = (char*)lA;
    char* lBc = (char*)lB;

    // 32x32x16 fragment geometry: A[row=lane&31][k=(lane>>5)*8+j], B symmetric.
    // Logical k-chunk for k-step ks: ks*2 + g1; physical = logical ^ ((row>>1)&3);
    // row = (32-multiple) + fr31 -> swizzle term = (fr31>>1)&3.
    const int fr31 = lane & 31;
    const int g1   = lane >> 5;
    const int sx0  = ((g1 ^ ((fr31 >> 1) & 3)) << 3);   // elements, k-step 0

    for (int k0 = 0; k0 < K; k0 += 32) {
        __syncthreads();   // protect LDS from overwrite while in use
        gld_lds16(A0 + k0, lAc + bo0);
        gld_lds16(A1 + k0, lAc + bo1);
        gld_lds16(B0 + k0, lBc + bo0);
        gld_lds16(B1 + k0, lBc + bo1);
        __syncthreads();

        #pragma unroll
        for (int ks = 0; ks < 2; ++ks) {
            const int sx = sx0 ^ (ks << 4);   // logical chunk +2 == element ^16
            bf16x8 af[2], bfv[2];
            #pragma unroll
            for (int mt = 0; mt < 2; ++mt)
                af[mt] = *(const bf16x8*)&lA[(wm + mt * 32 + fr31) * 32 + sx];
            #pragma unroll
            for (int nt = 0; nt < 2; ++nt)
                bfv[nt] = *(const bf16x8*)&lB[(wn + nt * 32 + fr31) * 32 + sx];
            #pragma unroll
            for (int mt = 0; mt < 2; ++mt)
                #pragma unroll
                for (int nt = 0; nt < 2; ++nt)
                    acc[mt][nt] = __builtin_amdgcn_mfma_f32_32x32x16_bf16(
                        af[mt], bfv[nt], acc[mt][nt], 0, 0, 0);
        }
    }

    // Epilogue. 32x32 C/D layout (m74/m101-verified):
    //   col = lane&31, row = (reg&3) + 8*(reg>>2) + 4*(lane>>5)
    const int col = lane & 31;

    if (mode == 2 && tn >= 8) {
        // V^T packed write: [b][d][s], 4 consecutive rows(s) per reg-quad.
        #pragma unroll
        for (int mt = 0; mt < 2; ++mt) {
            #pragma unroll
            for (int nt = 0; nt < 2; ++nt) {
                const int d = (n0 - 1024) + wn + nt * 32 + col;
                #pragma unroll
                for (int rg = 0; rg < 4; ++rg) {
                    const int s0q = m0 + wm + mt * 32 + 8 * rg + 4 * g1;
                    const int b  = s0q >> 11;       // S_=2048 rows per batch
                    const int se = s0q & (S_ - 1);
                    ushort4 u;
                    u.x = f2bf(acc[mt][nt][rg * 4 + 0]);
                    u.y = f2bf(acc[mt][nt][rg * 4 + 1]);
                    u.z = f2bf(acc[mt][nt][rg * 4 + 2]);
                    u.w = f2bf(acc[mt][nt][rg * 4 + 3]);
                    *(ushort4*)&Cv2[((size_t)b * D_ + d) * S_ + se] = u;
                }
            }
        }
    } else if (mode >= 1) {
        unsigned short* C = (unsigned short*)Cv + (long long)bz * sC;
        #pragma unroll
        for (int mt = 0; mt < 2; ++mt) {
            #pragma unroll
            for (int nt = 0; nt < 2; ++nt) {
                const int gc = n0 + wn + nt * 32 + col;
                #pragma unroll
                for (int reg = 0; reg < 16; ++reg) {
                    const int gr = m0 + wm + mt * 32 +
                                   (reg & 3) + 8 * (reg >> 2) + 4 * g1;
                    C[(size_t)gr * ldc + gc] = f2bf(acc[mt][nt][reg] * scale);
                }
            }
        }
    } else {
        float* C = (float*)Cv + (long long)bz * sC;
        #pragma unroll
        for (int mt = 0; mt < 2; ++mt) {
            #pragma unroll
            for (int nt = 0; nt < 2; ++nt) {
                const int gc = n0 + wn + nt * 32 + col;
                #pragma unroll
                for (int reg = 0; reg < 16; ++reg) {
                    const int gr = m0 + wm + mt * 32 +
                                   (reg & 3) + 8 * (reg >> 2) + 4 * g1;
                    C[(size_t)gr * ldc + gc] = acc[mt][nt][reg] * scale;
                }
            }
        }
    }
}

// ---------------------------------------------------------------------------
// fp32 -> bf16 convert, 4 elems/thread
// ---------------------------------------------------------------------------
__global__ __launch_bounds__(256) void convert_x4(const float* __restrict__ x,
                                                  unsigned short* __restrict__ xb) {
    const size_t i = ((size_t)blockIdx.x * 256 + threadIdx.x) * 4;
    const float4 f = *(const float4*)(x + i);
    ushort4 u;
    u.x = f2bf(f.x); u.y = f2bf(f.y); u.z = f2bf(f.z); u.w = f2bf(f.w);
    *(ushort4*)(xb + i) = u;
}

// W [D][D] (d,e) -> WT bf16 rows e (n), cols d (k); WQ|WK|WV stack to [3D][D].
__global__ __launch_bounds__(256) void convert_w(const float* __restrict__ WQ,
                                                 const float* __restrict__ WK,
                                                 const float* __restrict__ WV,
                                                 unsigned short* __restrict__ WT) {
    const int o = blockIdx.x * 256 + threadIdx.x;   // 0..D*D-1
    const float* W = blockIdx.y == 0 ? WQ : (blockIdx.y == 1 ? WK : WV);
    const int e = o >> 9, d = o & (D_ - 1);
    WT[(size_t)blockIdx.y * D_ * D_ + o] = f2bf(W[d * D_ + e]);
}

// ---------------------------------------------------------------------------
// Row softmax over S_ bf16 scores, in place. One block per row, 8 elems/thread,
// fp32 math, block reduce (wave shuffle + 4-slot LDS).
// ---------------------------------------------------------------------------
__global__ __launch_bounds__(256) void softmax_rows(unsigned short* __restrict__ Smat) {
    const int tid = threadIdx.x;
    unsigned short* row = Smat + (size_t)blockIdx.x * S_;
    const uint4 raw = *(const uint4*)(row + tid * 8);
    const unsigned ru[4] = {raw.x, raw.y, raw.z, raw.w};
    float v[8];
    #pragma unroll
    for (int i = 0; i < 4; ++i) {
        v[2 * i]     = __builtin_bit_cast(float, (ru[i] & 0xFFFFu) << 16);
        v[2 * i + 1] = __builtin_bit_cast(float, ru[i] & 0xFFFF0000u);
    }
    float m = v[0];
    #pragma unroll
    for (int i = 1; i < 8; ++i) m = fmaxf(m, v[i]);
    #pragma unroll
    for (int off = 32; off > 0; off >>= 1) m = fmaxf(m, __shfl_xor(m, off, 64));
    __shared__ float red[4];
    const int wave = tid >> 6, lane = tid & 63;
    if (lane == 0) red[wave] = m;
    __syncthreads();
    m = fmaxf(fmaxf(red[0], red[1]), fmaxf(red[2], red[3]));

    float e[8], s = 0.f;
    #pragma unroll
    for (int i = 0; i < 8; ++i) { e[i] = __expf(v[i] - m); s += e[i]; }
    #pragma unroll
    for (int off = 32; off > 0; off >>= 1) s += __shfl_xor(s, off, 64);
    __syncthreads();
    if (lane == 0) red[wave] = s;
    __syncthreads();
    const float inv = 1.0f / (red[0] + red[1] + red[2] + red[3]);

    uint4 o;
    unsigned ov[4];
    #pragma unroll
    for (int i = 0; i < 4; ++i)
        ov[i] = (unsigned)f2bf(e[2 * i] * inv) |
                ((unsigned)f2bf(e[2 * i + 1] * inv) << 16);
    o.x = ov[0]; o.y = ov[1]; o.z = ov[2]; o.w = ov[3];
    *(uint4*)(row + tid * 8) = o;
}

// ---------------------------------------------------------------------------
extern "C" void kernel_launch(void* const* d_in, const int* in_sizes, int n_in,
                              void* d_out, int out_size, void* d_ws, size_t ws_size,
                              hipStream_t stream)
{
    const float* x  = (const float*)d_in[0];
    const float* WQ = (const float*)d_in[1];
    const float* WK = (const float*)d_in[2];
    const float* WV = (const float*)d_in[3];

    // workspace layout (bf16 elements); ~136 MB total
    unsigned short* ws  = (unsigned short*)d_ws;
    const size_t NX = (size_t)B_ * S_ * D_;          // 8,388,608
    unsigned short* xb  = ws;                        // [16384][512]
    unsigned short* wtb = xb + NX;                   // [1536 n][512 k]
    unsigned short* qk  = wtb + 3 * D_ * D_;         // [16384][1024] (Q|K per row)
    unsigned short* vtb = qk + NX * 2;               // [b][d][s]
    unsigned short* sb  = vtb + NX;                  // [b][q][k] scores/P

    // 1) converts
    convert_x4<<<dim3((unsigned)(NX / 4 / 256)), 256, 0, stream>>>(x, xb);
    convert_w<<<dim3(D_ * D_ / 256, 3), 256, 0, stream>>>(WQ, WK, WV, wtb);

    // 2) fused QKV projection: Q|K -> qk [16384][1024]; V -> vtb transposed
    gemm_bt<<<dim3((B_ * S_ / 128) * (3 * D_ / 128)), 256, 0, stream>>>(
        xb, wtb, qk, vtb, D_, D_, D_, 2 * D_,
        0, 0, 0, 1.0f, 2, /*ntn*/ 3 * D_ / 128, /*nbatch*/ 1);

    // 3) scores = Q @ K^T * 1/sqrt(D), bf16, per batch (batch pinned to XCD)
    gemm_bt<<<dim3(B_ * (S_ / 128) * (S_ / 128)), 256, 0, stream>>>(
        qk /*Q*/, qk + D_ /*K*/, sb, nullptr, D_, 2 * D_, 2 * D_, S_,
        (long long)S_ * 2 * D_, (long long)S_ * 2 * D_, (long long)S_ * S_,
        0.04419417382415922f, 1, /*ntn*/ S_ / 128, /*nbatch*/ B_);

    // 4) softmax rows, in place (bf16)
    softmax_rows<<<dim3(B_ * S_), 256, 0, stream>>>(sb);

    // 5) out = P @ V (fp32 out), B^T operand = V^T [d][key]
    gemm_bt<<<dim3(B_ * (S_ / 128) * (D_ / 128)), 256, 0, stream>>>(
        sb, vtb, d_out, nullptr, S_, S_, S_, D_,
        (long long)S_ * S_, (long long)D_ * S_, (long long)S_ * D_,
        1.0f, 0, /*ntn*/ D_ / 128, /*nbatch*/ B_);
}